// Round 6
// baseline (183.312 us; speedup 1.0000x reference)
//
#include <hip/hip_runtime.h>

#define WIN 33
#define WIDTH 128
#define MPTS 64
#define NN 2048
#define MM 2048
#define DD 64
#define NQ 2080   // N + 2L

typedef __bf16 bf16x8 __attribute__((ext_vector_type(8)));
typedef float f32x4 __attribute__((ext_vector_type(4)));

__device__ __forceinline__ unsigned short f2bf(float x) {
  union { float f; unsigned int u; } v; v.f = x;
  unsigned int r = v.u + 0x7FFFu + ((v.u >> 16) & 1u);  // RNE
  return (unsigned short)(r >> 16);
}
__device__ __forceinline__ float sigf(float x) { return 1.0f / (1.0f + __expf(-x)); }

// async global->LDS, 16B per lane, fire-and-forget (drained by vmcnt at barrier)
__device__ __forceinline__ void gll16(const unsigned short* g, unsigned short* l) {
  __builtin_amdgcn_global_load_lds(
      (const __attribute__((address_space(1))) unsigned int*)g,
      (__attribute__((address_space(3))) unsigned int*)l, 16, 0, 0);
}

// ------------- fused prep: MLP (bid<33) + transpose (bid>=33) + out-zero ---
__global__ __launch_bounds__(256) void k_prep(const float* __restrict__ xi,
                                              unsigned short* __restrict__ xiT,
                                              const float* __restrict__ u,
                                              const float* __restrict__ w0,
                                              const float* __restrict__ b0,
                                              const float* __restrict__ w,
                                              const float* __restrict__ bias,
                                              unsigned short* __restrict__ u1bf,
                                              float* __restrict__ out) {
  extern __shared__ char smem[];
  int bid = blockIdx.x;
  int tid = threadIdx.x;

  if (bid < 33) {
    // ---------------- MLP branch ----------------
    constexpr int WS = 72;
    constexpr int AS = 136;
    float* biass = (float*)smem;                              // 512 B
    unsigned short* ws   = (unsigned short*)(smem + 512);     // 18,432 B
    unsigned short* actA = (unsigned short*)(smem + 18944);   // 17,408 B
    unsigned short* actB = (unsigned short*)(smem + 36352);   // 17,408 B
    int j = bid;
    int wv = tid >> 6, lane = tid & 63, l15 = lane & 15, l4 = lane >> 4;

#pragma unroll
    for (int c = tid; c < 1024; c += 256) {
      int p = c >> 4, d4 = (c & 15) << 2;
      float4 v = *(const float4*)&u[(size_t)p * DD + d4];
      ushort4 h; h.x = f2bf(v.x); h.y = f2bf(v.y); h.z = f2bf(v.z); h.w = f2bf(v.w);
      *(ushort4*)&actA[p * AS + d4] = h;
    }
#pragma unroll
    for (int c = tid; c < 2048; c += 256) {
      int k = c >> 4, d4 = (c & 15) << 2;
      float4 v = *(const float4*)&w0[((size_t)j * 128 + k) * DD + d4];
      ushort4 h; h.x = f2bf(v.x); h.y = f2bf(v.y); h.z = f2bf(v.z); h.w = f2bf(v.w);
      *(ushort4*)&ws[k * WS + d4] = h;
    }
    if (tid < 128) biass[tid] = b0[j * 128 + tid];
    __syncthreads();

    {  // layer 0: K=64
      f32x4 acc[2][4] = {};
#pragma unroll
      for (int t = 0; t < 2; ++t) {
        int col = (t << 5) + (l4 << 3);
        bf16x8 a[2], b[4];
#pragma unroll
        for (int s = 0; s < 2; ++s)
          a[s] = *(const bf16x8*)&ws[(wv * 32 + s * 16 + l15) * WS + col];
#pragma unroll
        for (int q = 0; q < 4; ++q)
          b[q] = *(const bf16x8*)&actA[(q * 16 + l15) * AS + col];
#pragma unroll
        for (int s = 0; s < 2; ++s)
#pragma unroll
          for (int q = 0; q < 4; ++q)
            acc[s][q] = __builtin_amdgcn_mfma_f32_16x16x32_bf16(a[s], b[q], acc[s][q], 0, 0, 0);
      }
#pragma unroll
      for (int s = 0; s < 2; ++s)
#pragma unroll
        for (int q = 0; q < 4; ++q) {
          int p = q * 16 + l15;
#pragma unroll
          for (int r = 0; r < 4; ++r) {
            int k = wv * 32 + s * 16 + (l4 << 2) + r;
            actB[p * AS + k] = f2bf(sigf(acc[s][q][r] + biass[k]));
          }
        }
    }

    unsigned short* ain = actB;
    unsigned short* aout = actA;
#pragma unroll
    for (int i = 0; i < 2; ++i) {
      f32x4 acc[2][4] = {};
      const float* wbase = w + ((size_t)i * WIN + j) * 128 * 128;
#pragma unroll
      for (int h = 0; h < 2; ++h) {
        __syncthreads();
#pragma unroll
        for (int c = tid; c < 2048; c += 256) {
          int k = c >> 4, d4 = (c & 15) << 2;
          float4 v = *(const float4*)&wbase[(size_t)k * 128 + h * 64 + d4];
          ushort4 hh; hh.x = f2bf(v.x); hh.y = f2bf(v.y); hh.z = f2bf(v.z); hh.w = f2bf(v.w);
          *(ushort4*)&ws[k * WS + d4] = hh;
        }
        if (h == 0 && tid < 128) biass[tid] = bias[((size_t)i * WIN + j) * 128 + tid];
        __syncthreads();
#pragma unroll
        for (int t = 0; t < 2; ++t) {
          int col = (t << 5) + (l4 << 3);
          bf16x8 a[2], b[4];
#pragma unroll
          for (int s = 0; s < 2; ++s)
            a[s] = *(const bf16x8*)&ws[(wv * 32 + s * 16 + l15) * WS + col];
#pragma unroll
          for (int q = 0; q < 4; ++q)
            b[q] = *(const bf16x8*)&ain[(q * 16 + l15) * AS + h * 64 + col];
#pragma unroll
          for (int s = 0; s < 2; ++s)
#pragma unroll
            for (int q = 0; q < 4; ++q)
              acc[s][q] = __builtin_amdgcn_mfma_f32_16x16x32_bf16(a[s], b[q], acc[s][q], 0, 0, 0);
        }
      }
#pragma unroll
      for (int s = 0; s < 2; ++s)
#pragma unroll
        for (int q = 0; q < 4; ++q) {
          int p = q * 16 + l15;
#pragma unroll
          for (int r = 0; r < 4; ++r) {
            int k = wv * 32 + s * 16 + (l4 << 2) + r;
            aout[p * AS + k] = f2bf(sigf(acc[s][q][r] + biass[k]));
          }
        }
      unsigned short* t2 = ain; ain = aout; aout = t2;
    }
    __syncthreads();
#pragma unroll
    for (int c = tid; c < 1024; c += 256) {
      int p = c >> 4, k8 = (c & 15) << 3;
      uint4 v = *(const uint4*)&ain[p * AS + k8];
      *(uint4*)&u1bf[((size_t)j * MPTS + p) * WIDTH + k8] = v;
    }
  } else {
    // ---------------- transpose branch ----------------
    float* ts = (float*)smem;                // 64*37*4 = 9,472 B
    int t = bid - 33;                        // [0, 2080)
    if (t < 512 && tid < 64) {               // zero out (512 x 1KB = 512KB)
      float4 z = {0.f, 0.f, 0.f, 0.f};
      *(float4*)&out[((size_t)t << 8) + (tid << 2)] = z;
    }
    int qt = t % 65, mt = t / 65;
    int qb = qt * 32;                        // 65 tiles over NQ=2080
    int mb = mt * 64;                        // 32 tiles over M=2048
#pragma unroll
    for (int c = tid; c < 512; c += 256) {   // 64 rows x 8 float4
      int row = c >> 3, c8 = c & 7;
      float4 v = *(const float4*)&xi[(size_t)(mb + row) * NQ + qb + (c8 << 2)];
      ts[row * 37 + (c8 << 2) + 0] = v.x;
      ts[row * 37 + (c8 << 2) + 1] = v.y;
      ts[row * 37 + (c8 << 2) + 2] = v.z;
      ts[row * 37 + (c8 << 2) + 3] = v.w;
    }
    __syncthreads();
#pragma unroll
    for (int c = tid; c < 512; c += 256) {   // 32 q-rows x 16 m-quads
      int r = c >> 4, mq = c & 15;
      ushort4 h;
      h.x = f2bf(ts[(mq * 4 + 0) * 37 + r]);
      h.y = f2bf(ts[(mq * 4 + 1) * 37 + r]);
      h.z = f2bf(ts[(mq * 4 + 2) * 37 + r]);
      h.w = f2bf(ts[(mq * 4 + 3) * 37 + r]);
      *(ushort4*)&xiT[((size_t)mt * NQ + (qb + r)) * 64 + (mq << 2)] = h;
    }
  }
}

// ------------- phase B: Gt2 in k_conv staging order -----------------------
// Gt2[region = mp*2+half][j=33][g=4][p=64][8m], region = 67,584 shorts.
__global__ __launch_bounds__(256) void k_final(const float* __restrict__ wf,
                                               const float* __restrict__ bfin,
                                               const unsigned short* __restrict__ u1bf,
                                               unsigned short* __restrict__ Gt2) {
  constexpr int KP = 136;
  __shared__ unsigned short As[64 * KP];
  __shared__ unsigned short Bs[64 * KP];
  __shared__ float bfs[64];
  int bid = blockIdx.x;                    // 33*32
  int j = bid >> 5;
  int m0 = (bid & 31) << 6;
#pragma unroll
  for (int c = threadIdx.x; c < 64 * 32; c += 256) {
    int row = c >> 5, f4 = c & 31;
    float4 v = *(const float4*)(wf + ((size_t)(m0 + row) * WIN + j) * WIDTH + (f4 << 2));
    ushort4 h;
    h.x = f2bf(v.x); h.y = f2bf(v.y); h.z = f2bf(v.z); h.w = f2bf(v.w);
    *(ushort4*)(&As[row * KP + (f4 << 2)]) = h;
  }
#pragma unroll
  for (int c = threadIdx.x; c < 64 * 16; c += 256) {
    int p = c >> 4, ch = c & 15;
    uint4 v = *(const uint4*)(u1bf + (size_t)(j * MPTS + p) * WIDTH + (ch << 3));
    *(uint4*)(&Bs[p * KP + (ch << 3)]) = v;
  }
  if (threadIdx.x < 64) bfs[threadIdx.x] = bfin[(size_t)(m0 + threadIdx.x) * WIN + j];
  __syncthreads();
  int wv = threadIdx.x >> 6, lane = threadIdx.x & 63;
  int l15 = lane & 15, l4 = lane >> 4;
  f32x4 acc[4] = {};
#pragma unroll
  for (int t = 0; t < 4; ++t) {
    int col = (t << 5) + (l4 << 3);
    bf16x8 a = *(const bf16x8*)(&As[(wv * 16 + l15) * KP + col]);
#pragma unroll
    for (int q = 0; q < 4; ++q) {
      bf16x8 bb = *(const bf16x8*)(&Bs[(q * 16 + l15) * KP + col]);
      acc[q] = __builtin_amdgcn_mfma_f32_16x16x32_bf16(a, bb, acc[q], 0, 0, 0);
    }
  }
  // m_local = wv*16 + l4*4 + i  ->  half = wv>>1, g = (wv&1)*2 + (l4>>1),
  // m8 = (l4&1)*4. Stores hit 2x256B contiguous runs per wave instruction.
  size_t region = (size_t)((bid & 31) << 1) + (wv >> 1);
  int g = ((wv & 1) << 1) + (l4 >> 1);
  int m8 = (l4 & 1) << 2;
  int mb = wv * 16 + (l4 << 2);
#pragma unroll
  for (int q = 0; q < 4; ++q) {
    int p = q * 16 + l15;
    float z0 = acc[q][0] + bfs[mb + 0];
    float z1 = acc[q][1] + bfs[mb + 1];
    float z2 = acc[q][2] + bfs[mb + 2];
    float z3 = acc[q][3] + bfs[mb + 3];
    ushort4 st;
    st.x = f2bf(sigf(z0)); st.y = f2bf(sigf(z1));
    st.z = f2bf(sigf(z2)); st.w = f2bf(sigf(z3));
    *(ushort4*)(&Gt2[region * 67584 + ((size_t)(j * 4 + g) * 64 + p) * 8 + m8]) = st;
  }
}

// ------------- phase C: out[n,p] += sum_{j,m} xiT[n+j,m] * Gt2[j,p,m] ------
// vs R5: j-PARTITIONED waves. R1 counters (MfmaUtil 13.7, VALU 7, HBM 2%,
// conflicts 0) + arithmetic say this kernel is LDS-read-bound: 6 ds_read_b128
// per 8 MFMA per wave, all 4 waves reading the SAME b-frags. Now each wave
// owns j = wv (mod 4) and computes the FULL 128n x 64p tile for its j's:
// 12 reads per 32 MFMA (0.375 vs 0.75), zero cross-wave B redundancy.
// Per-CU LDS traffic 3.17MB -> 1.58MB (floor ~15.5us -> ~7.7us).
// acc[8][4] = 128 VGPR (launch_bounds(256,2) caps at 256, 2 blocks/CU kept).
// Epilogue: 4-pass LDS reduction across waves, then same 32 atomics/thread.
// Staging pipeline / layouts / swizzle byte-identical to R5.
__global__ __launch_bounds__(256, 2) void k_conv(const unsigned short* __restrict__ xiT,
                                                 const unsigned short* __restrict__ Gt2,
                                                 float* __restrict__ out) {
  extern __shared__ unsigned short lds[];
  unsigned short* As = lds;                // [160][64] swizzled = 20,480 B
  int bid = blockIdx.x;
  int mp = bid & 31;                       // bid%8 == mp%8 -> same-B blocks share an XCD
  int n0 = (bid >> 5) << 7;                // 16 n-tiles of 128
  int tid = threadIdx.x;
  int wv = tid >> 6, lane = tid & 63, l15 = lane & 15, l4 = lane >> 4;

  // ---- stage A once: contiguous 1KB per instr; XOR permute (c ^= row&7)
  const unsigned short* Abase = xiT + (size_t)mp * (NQ * 64) + (size_t)n0 * 64;
#pragma unroll
  for (int k = 0; k < 5; ++k) {
    int instr = wv * 5 + k;                // 20 wave-instructions
    int s = (instr << 6) + lane;
    int row = s >> 3;
    int c = (s & 7) ^ (row & 7);
    gll16(Abase + (size_t)row * 64 + (c << 3), As + (instr << 9));
  }

  // phase tables: t = half*5 + p
  constexpr int JBT[10]  = {0, 7, 14, 21, 28, 0, 7, 14, 21, 28};
  constexpr int CNTT[10] = {7, 7, 7, 7, 5, 7, 7, 7, 7, 5};
  constexpr int HFT[10]  = {0, 0, 0, 0, 0, 1, 1, 1, 1, 1};

  const unsigned short* Rb0 = Gt2 + (size_t)(mp << 1) * 67584;        // half 0
  const unsigned short* Rb1 = Gt2 + (size_t)((mp << 1) + 1) * 67584;  // half 1

  // ---- prologue: issue B(phase 0) into buf0
  {
    const unsigned short* Bb = Rb0;        // jb=0
#pragma unroll
    for (int k = 0; k < 7; ++k) {
      int instr = wv * 7 + k;
      gll16(Bb + (((instr << 6) + lane) << 3), lds + 10240 + (instr << 9));
    }
  }

  f32x4 acc[8][4] = {};
#pragma unroll
  for (int t = 0; t < 10; ++t) {
    __syncthreads();   // drains own vmcnt(0): A + B(t) ready; all waves done
                       // reading the buffer about to be overwritten.
    if (t < 9) {       // issue B(t+1) into buf[(t+1)&1]; lands during compute(t)
      const int jbn = JBT[t + 1], cntn = CNTT[t + 1];
      const unsigned short* Bb =
          (HFT[t + 1] ? Rb1 : Rb0) + ((size_t)jbn << 11);
      unsigned short* Bst = lds + 10240 + ((t + 1) & 1) * 14336;
#pragma unroll
      for (int k = 0; k < cntn; ++k) {
        int instr = wv * cntn + k;
        gll16(Bb + (((instr << 6) + lane) << 3), Bst + (instr << 9));
      }
    }
    // ---- compute phase t from buf[t&1]; wave handles j = jb+wv, jb+wv+4
    {
      const int jb = JBT[t], cnt = CNTT[t], h4 = HFT[t] << 2;
      const unsigned short* Bs = lds + 10240 + (t & 1) * 14336;
#pragma unroll
      for (int r = 0; r < 2; ++r) {
        int jj = wv + (r << 2);
        if (jj < cnt) {
          bf16x8 a[8], b[4];
#pragma unroll
          for (int g = 0; g < 8; ++g) {
            int row = (g << 4) + l15 + jb + jj;
            a[g] = *(const bf16x8*)&As[row * 64 + (((h4 | l4) ^ (row & 7)) << 3)];
          }
#pragma unroll
          for (int q = 0; q < 4; ++q) {
            int slot = (((jj << 2) + l4) << 6) + (q << 4) + l15;
            b[q] = *(const bf16x8*)&Bs[slot << 3];
          }
#pragma unroll
          for (int g = 0; g < 8; ++g)
#pragma unroll
            for (int q = 0; q < 4; ++q)
              acc[g][q] = __builtin_amdgcn_mfma_f32_16x16x32_bf16(a[g], b[q], acc[g][q], 0, 0, 0);
        }
      }
    }
  }

  // ---- cross-wave reduction (j was partitioned): 4 sequential LDS passes
  float* red = (float*)lds;                // 128 x 64 f32 = 32,768 B
#pragma unroll 1
  for (int w = 0; w < 4; ++w) {
    __syncthreads();                       // w=0: also guards As/Bs reuse
    if (wv == w) {
#pragma unroll
      for (int g = 0; g < 8; ++g)
#pragma unroll
        for (int q = 0; q < 4; ++q)
#pragma unroll
          for (int i = 0; i < 4; ++i) {
            int idx = (((g << 4) + (l4 << 2) + i) << 6) + (q << 4) + l15;
            if (w == 0) red[idx] = acc[g][q][i];
            else        red[idx] += acc[g][q][i];
          }
    }
  }
  __syncthreads();
  for (int c = tid; c < 8192; c += 256)
    atomicAdd(&out[((size_t)(n0 + (c >> 6)) << 6) + (c & 63)], red[c]);
}

extern "C" void kernel_launch(void* const* d_in, const int* in_sizes, int n_in,
                              void* d_out, int out_size, void* d_ws, size_t ws_size,
                              hipStream_t stream) {
  const float* u    = (const float*)d_in[0];  // [64,64]
  const float* w0   = (const float*)d_in[1];  // [33,128,64]
  const float* b0   = (const float*)d_in[2];  // [33,128,1]
  const float* w    = (const float*)d_in[3];  // [2,33,128,128]
  const float* bias = (const float*)d_in[4];  // [2,33,128,1]
  const float* wf   = (const float*)d_in[5];  // [2048,33,128]
  const float* bfin = (const float*)d_in[6];  // [2048,33,1]
  const float* xi   = (const float*)d_in[7];  // [2048,2080]
  float* out = (float*)d_out;                 // [2048,64]
  char* ws = (char*)d_ws;
  unsigned short* xiT  = (unsigned short*)(ws);             // 8,519,680 B
  unsigned short* Gt2  = (unsigned short*)(ws + 8519680);   // 8,650,752 B
  unsigned short* u1bf = (unsigned short*)(ws + 17170432);  // 540,672 B

  hipFuncSetAttribute(reinterpret_cast<const void*>(&k_prep),
                      hipFuncAttributeMaxDynamicSharedMemorySize, 53760);
  hipFuncSetAttribute(reinterpret_cast<const void*>(&k_conv),
                      hipFuncAttributeMaxDynamicSharedMemorySize, 77824);

  k_prep<<<2113, 256, 53760, stream>>>(xi, xiT, u, w0, b0, w, bias, u1bf, out);
  k_final<<<33 * 32, 256, 0, stream>>>(wf, bfin, u1bf, Gt2);
  k_conv<<<512, 256, 77824, stream>>>(xiT, Gt2, out);
}

// Round 7
// 155.193 us; speedup vs baseline: 1.1812x; 1.1812x over previous
//
#include <hip/hip_runtime.h>

#define WIN 33
#define WIDTH 128
#define MPTS 64
#define NN 2048
#define MM 2048
#define DD 64
#define NQ 2080   // N + 2L

typedef __bf16 bf16x8 __attribute__((ext_vector_type(8)));
typedef float f32x4 __attribute__((ext_vector_type(4)));

__device__ __forceinline__ unsigned short f2bf(float x) {
  union { float f; unsigned int u; } v; v.f = x;
  unsigned int r = v.u + 0x7FFFu + ((v.u >> 16) & 1u);  // RNE
  return (unsigned short)(r >> 16);
}
__device__ __forceinline__ float sigf(float x) { return 1.0f / (1.0f + __expf(-x)); }

// async global->LDS, 16B per lane, fire-and-forget (drained by vmcnt at barrier)
__device__ __forceinline__ void gll16(const unsigned short* g, unsigned short* l) {
  __builtin_amdgcn_global_load_lds(
      (const __attribute__((address_space(1))) unsigned int*)g,
      (__attribute__((address_space(3))) unsigned int*)l, 16, 0, 0);
}

// ------------- fused prep: MLP (bid<33) + transpose (bid>=33) + out-zero ---
__global__ __launch_bounds__(256) void k_prep(const float* __restrict__ xi,
                                              unsigned short* __restrict__ xiT,
                                              const float* __restrict__ u,
                                              const float* __restrict__ w0,
                                              const float* __restrict__ b0,
                                              const float* __restrict__ w,
                                              const float* __restrict__ bias,
                                              unsigned short* __restrict__ u1bf,
                                              float* __restrict__ out) {
  extern __shared__ char smem[];
  int bid = blockIdx.x;
  int tid = threadIdx.x;

  if (bid < 33) {
    // ---------------- MLP branch ----------------
    constexpr int WS = 72;
    constexpr int AS = 136;
    float* biass = (float*)smem;                              // 512 B
    unsigned short* ws   = (unsigned short*)(smem + 512);     // 18,432 B
    unsigned short* actA = (unsigned short*)(smem + 18944);   // 17,408 B
    unsigned short* actB = (unsigned short*)(smem + 36352);   // 17,408 B
    int j = bid;
    int wv = tid >> 6, lane = tid & 63, l15 = lane & 15, l4 = lane >> 4;

#pragma unroll
    for (int c = tid; c < 1024; c += 256) {
      int p = c >> 4, d4 = (c & 15) << 2;
      float4 v = *(const float4*)&u[(size_t)p * DD + d4];
      ushort4 h; h.x = f2bf(v.x); h.y = f2bf(v.y); h.z = f2bf(v.z); h.w = f2bf(v.w);
      *(ushort4*)&actA[p * AS + d4] = h;
    }
#pragma unroll
    for (int c = tid; c < 2048; c += 256) {
      int k = c >> 4, d4 = (c & 15) << 2;
      float4 v = *(const float4*)&w0[((size_t)j * 128 + k) * DD + d4];
      ushort4 h; h.x = f2bf(v.x); h.y = f2bf(v.y); h.z = f2bf(v.z); h.w = f2bf(v.w);
      *(ushort4*)&ws[k * WS + d4] = h;
    }
    if (tid < 128) biass[tid] = b0[j * 128 + tid];
    __syncthreads();

    {  // layer 0: K=64
      f32x4 acc[2][4] = {};
#pragma unroll
      for (int t = 0; t < 2; ++t) {
        int col = (t << 5) + (l4 << 3);
        bf16x8 a[2], b[4];
#pragma unroll
        for (int s = 0; s < 2; ++s)
          a[s] = *(const bf16x8*)&ws[(wv * 32 + s * 16 + l15) * WS + col];
#pragma unroll
        for (int q = 0; q < 4; ++q)
          b[q] = *(const bf16x8*)&actA[(q * 16 + l15) * AS + col];
#pragma unroll
        for (int s = 0; s < 2; ++s)
#pragma unroll
          for (int q = 0; q < 4; ++q)
            acc[s][q] = __builtin_amdgcn_mfma_f32_16x16x32_bf16(a[s], b[q], acc[s][q], 0, 0, 0);
      }
#pragma unroll
      for (int s = 0; s < 2; ++s)
#pragma unroll
        for (int q = 0; q < 4; ++q) {
          int p = q * 16 + l15;
#pragma unroll
          for (int r = 0; r < 4; ++r) {
            int k = wv * 32 + s * 16 + (l4 << 2) + r;
            actB[p * AS + k] = f2bf(sigf(acc[s][q][r] + biass[k]));
          }
        }
    }

    unsigned short* ain = actB;
    unsigned short* aout = actA;
#pragma unroll
    for (int i = 0; i < 2; ++i) {
      f32x4 acc[2][4] = {};
      const float* wbase = w + ((size_t)i * WIN + j) * 128 * 128;
#pragma unroll
      for (int h = 0; h < 2; ++h) {
        __syncthreads();
#pragma unroll
        for (int c = tid; c < 2048; c += 256) {
          int k = c >> 4, d4 = (c & 15) << 2;
          float4 v = *(const float4*)&wbase[(size_t)k * 128 + h * 64 + d4];
          ushort4 hh; hh.x = f2bf(v.x); hh.y = f2bf(v.y); hh.z = f2bf(v.z); hh.w = f2bf(v.w);
          *(ushort4*)&ws[k * WS + d4] = hh;
        }
        if (h == 0 && tid < 128) biass[tid] = bias[((size_t)i * WIN + j) * 128 + tid];
        __syncthreads();
#pragma unroll
        for (int t = 0; t < 2; ++t) {
          int col = (t << 5) + (l4 << 3);
          bf16x8 a[2], b[4];
#pragma unroll
          for (int s = 0; s < 2; ++s)
            a[s] = *(const bf16x8*)&ws[(wv * 32 + s * 16 + l15) * WS + col];
#pragma unroll
          for (int q = 0; q < 4; ++q)
            b[q] = *(const bf16x8*)&ain[(q * 16 + l15) * AS + h * 64 + col];
#pragma unroll
          for (int s = 0; s < 2; ++s)
#pragma unroll
            for (int q = 0; q < 4; ++q)
              acc[s][q] = __builtin_amdgcn_mfma_f32_16x16x32_bf16(a[s], b[q], acc[s][q], 0, 0, 0);
        }
      }
#pragma unroll
      for (int s = 0; s < 2; ++s)
#pragma unroll
        for (int q = 0; q < 4; ++q) {
          int p = q * 16 + l15;
#pragma unroll
          for (int r = 0; r < 4; ++r) {
            int k = wv * 32 + s * 16 + (l4 << 2) + r;
            aout[p * AS + k] = f2bf(sigf(acc[s][q][r] + biass[k]));
          }
        }
      unsigned short* t2 = ain; ain = aout; aout = t2;
    }
    __syncthreads();
#pragma unroll
    for (int c = tid; c < 1024; c += 256) {
      int p = c >> 4, k8 = (c & 15) << 3;
      uint4 v = *(const uint4*)&ain[p * AS + k8];
      *(uint4*)&u1bf[((size_t)j * MPTS + p) * WIDTH + k8] = v;
    }
  } else {
    // ---------------- transpose branch ----------------
    float* ts = (float*)smem;                // 64*37*4 = 9,472 B
    int t = bid - 33;                        // [0, 2080)
    if (t < 512 && tid < 64) {               // zero out (512 x 1KB = 512KB)
      float4 z = {0.f, 0.f, 0.f, 0.f};
      *(float4*)&out[((size_t)t << 8) + (tid << 2)] = z;
    }
    int qt = t % 65, mt = t / 65;
    int qb = qt * 32;                        // 65 tiles over NQ=2080
    int mb = mt * 64;                        // 32 tiles over M=2048
#pragma unroll
    for (int c = tid; c < 512; c += 256) {   // 64 rows x 8 float4
      int row = c >> 3, c8 = c & 7;
      float4 v = *(const float4*)&xi[(size_t)(mb + row) * NQ + qb + (c8 << 2)];
      ts[row * 37 + (c8 << 2) + 0] = v.x;
      ts[row * 37 + (c8 << 2) + 1] = v.y;
      ts[row * 37 + (c8 << 2) + 2] = v.z;
      ts[row * 37 + (c8 << 2) + 3] = v.w;
    }
    __syncthreads();
#pragma unroll
    for (int c = tid; c < 512; c += 256) {   // 32 q-rows x 16 m-quads
      int r = c >> 4, mq = c & 15;
      ushort4 h;
      h.x = f2bf(ts[(mq * 4 + 0) * 37 + r]);
      h.y = f2bf(ts[(mq * 4 + 1) * 37 + r]);
      h.z = f2bf(ts[(mq * 4 + 2) * 37 + r]);
      h.w = f2bf(ts[(mq * 4 + 3) * 37 + r]);
      *(ushort4*)&xiT[((size_t)mt * NQ + (qb + r)) * 64 + (mq << 2)] = h;
    }
  }
}

// ------------- phase B: Gt2 in k_conv staging order -----------------------
// Gt2[region = mp*2+half][j=33][g=4][p=64][8m], region = 67,584 shorts.
__global__ __launch_bounds__(256) void k_final(const float* __restrict__ wf,
                                               const float* __restrict__ bfin,
                                               const unsigned short* __restrict__ u1bf,
                                               unsigned short* __restrict__ Gt2) {
  constexpr int KP = 136;
  __shared__ unsigned short As[64 * KP];
  __shared__ unsigned short Bs[64 * KP];
  __shared__ float bfs[64];
  int bid = blockIdx.x;                    // 33*32
  int j = bid >> 5;
  int m0 = (bid & 31) << 6;
#pragma unroll
  for (int c = threadIdx.x; c < 64 * 32; c += 256) {
    int row = c >> 5, f4 = c & 31;
    float4 v = *(const float4*)(wf + ((size_t)(m0 + row) * WIN + j) * WIDTH + (f4 << 2));
    ushort4 h;
    h.x = f2bf(v.x); h.y = f2bf(v.y); h.z = f2bf(v.z); h.w = f2bf(v.w);
    *(ushort4*)(&As[row * KP + (f4 << 2)]) = h;
  }
#pragma unroll
  for (int c = threadIdx.x; c < 64 * 16; c += 256) {
    int p = c >> 4, ch = c & 15;
    uint4 v = *(const uint4*)(u1bf + (size_t)(j * MPTS + p) * WIDTH + (ch << 3));
    *(uint4*)(&Bs[p * KP + (ch << 3)]) = v;
  }
  if (threadIdx.x < 64) bfs[threadIdx.x] = bfin[(size_t)(m0 + threadIdx.x) * WIN + j];
  __syncthreads();
  int wv = threadIdx.x >> 6, lane = threadIdx.x & 63;
  int l15 = lane & 15, l4 = lane >> 4;
  f32x4 acc[4] = {};
#pragma unroll
  for (int t = 0; t < 4; ++t) {
    int col = (t << 5) + (l4 << 3);
    bf16x8 a = *(const bf16x8*)(&As[(wv * 16 + l15) * KP + col]);
#pragma unroll
    for (int q = 0; q < 4; ++q) {
      bf16x8 bb = *(const bf16x8*)(&Bs[(q * 16 + l15) * KP + col]);
      acc[q] = __builtin_amdgcn_mfma_f32_16x16x32_bf16(a, bb, acc[q], 0, 0, 0);
    }
  }
  // m_local = wv*16 + l4*4 + i  ->  half = wv>>1, g = (wv&1)*2 + (l4>>1),
  // m8 = (l4&1)*4. Stores hit 2x256B contiguous runs per wave instruction.
  size_t region = (size_t)((bid & 31) << 1) + (wv >> 1);
  int g = ((wv & 1) << 1) + (l4 >> 1);
  int m8 = (l4 & 1) << 2;
  int mb = wv * 16 + (l4 << 2);
#pragma unroll
  for (int q = 0; q < 4; ++q) {
    int p = q * 16 + l15;
    float z0 = acc[q][0] + bfs[mb + 0];
    float z1 = acc[q][1] + bfs[mb + 1];
    float z2 = acc[q][2] + bfs[mb + 2];
    float z3 = acc[q][3] + bfs[mb + 3];
    ushort4 st;
    st.x = f2bf(sigf(z0)); st.y = f2bf(sigf(z1));
    st.z = f2bf(sigf(z2)); st.w = f2bf(sigf(z3));
    *(ushort4*)(&Gt2[region * 67584 + ((size_t)(j * 4 + g) * 64 + p) * 8 + m8]) = st;
  }
}

// ------------- phase C: out[n,p] += sum_{j,m} xiT[n+j,m] * Gt2[j,p,m] ------
// R7 = exact R5 structure (R6's j-partition regressed 2x: broken pipeline,
// wave imbalance, serialized conflicted reduction -> reverted) + T5
// s_setprio around the compute cluster. Mechanism: 2 independent blocks/CU
// at unsynchronized phases; setprio biases the SIMD scheduler toward the
// block in its MFMA cluster over the block issuing staging (m191 regime).
__global__ __launch_bounds__(256) void k_conv(const unsigned short* __restrict__ xiT,
                                              const unsigned short* __restrict__ Gt2,
                                              float* __restrict__ out) {
  extern __shared__ unsigned short lds[];
  unsigned short* As = lds;                // [160][64] swizzled = 20,480 B
  int bid = blockIdx.x;
  int mp = bid & 31;                       // bid%8 == mp%8 -> same-B blocks share an XCD
  int n0 = (bid >> 5) << 7;                // 16 n-tiles of 128
  int tid = threadIdx.x;
  int wv = tid >> 6, lane = tid & 63, l15 = lane & 15, l4 = lane >> 4;

  // ---- stage A once: contiguous 1KB per instr; XOR permute (c ^= row&7)
  const unsigned short* Abase = xiT + (size_t)mp * (NQ * 64) + (size_t)n0 * 64;
#pragma unroll
  for (int k = 0; k < 5; ++k) {
    int instr = wv * 5 + k;                // 20 wave-instructions
    int s = (instr << 6) + lane;
    int row = s >> 3;
    int c = (s & 7) ^ (row & 7);
    gll16(Abase + (size_t)row * 64 + (c << 3), As + (instr << 9));
  }

  // phase tables: t = half*5 + p
  constexpr int JBT[10]  = {0, 7, 14, 21, 28, 0, 7, 14, 21, 28};
  constexpr int CNTT[10] = {7, 7, 7, 7, 5, 7, 7, 7, 7, 5};
  constexpr int HFT[10]  = {0, 0, 0, 0, 0, 1, 1, 1, 1, 1};

  const unsigned short* Rb0 = Gt2 + (size_t)(mp << 1) * 67584;        // half 0
  const unsigned short* Rb1 = Gt2 + (size_t)((mp << 1) + 1) * 67584;  // half 1

  // ---- prologue: issue B(phase 0) into buf0
  {
    const unsigned short* Bb = Rb0;        // jb=0
#pragma unroll
    for (int k = 0; k < 7; ++k) {
      int instr = wv * 7 + k;
      gll16(Bb + (((instr << 6) + lane) << 3), lds + 10240 + (instr << 9));
    }
  }

  f32x4 acc[2][4] = {};
#pragma unroll
  for (int t = 0; t < 10; ++t) {
    __syncthreads();   // drains own vmcnt(0): A + B(t) ready; all waves done
                       // reading the buffer about to be overwritten.
    if (t < 9) {       // issue B(t+1) into buf[(t+1)&1]; lands during compute(t)
      const int jbn = JBT[t + 1], cntn = CNTT[t + 1];
      const unsigned short* Bb =
          (HFT[t + 1] ? Rb1 : Rb0) + ((size_t)jbn << 11);
      unsigned short* Bst = lds + 10240 + ((t + 1) & 1) * 14336;
#pragma unroll
      for (int k = 0; k < cntn; ++k) {
        int instr = wv * cntn + k;
        gll16(Bb + (((instr << 6) + lane) << 3), Bst + (instr << 9));
      }
    }
    // ---- compute phase t from buf[t&1]
    {
      const int jb = JBT[t], cnt = CNTT[t], h4 = HFT[t] << 2;
      const unsigned short* Bs = lds + 10240 + (t & 1) * 14336;
      bf16x8 a[2], b[4];
#pragma unroll
      for (int s = 0; s < 2; ++s) {
        int row = wv * 32 + s * 16 + l15 + jb;
        a[s] = *(const bf16x8*)&As[row * 64 + (((h4 | l4) ^ (row & 7)) << 3)];
      }
#pragma unroll
      for (int q = 0; q < 4; ++q) {
        int slot = (l4 << 6) + (q << 4) + l15;
        b[q] = *(const bf16x8*)&Bs[slot << 3];
      }
      __builtin_amdgcn_s_setprio(1);       // T5: favor compute cluster
#pragma unroll
      for (int jj = 0; jj < cnt; ++jj) {
        bf16x8 an[2], bn[4];
        if (jj < cnt - 1) {                // prefetch j+1 while computing j
#pragma unroll
          for (int s = 0; s < 2; ++s) {
            int row = wv * 32 + s * 16 + l15 + jb + jj + 1;
            an[s] = *(const bf16x8*)&As[row * 64 + (((h4 | l4) ^ (row & 7)) << 3)];
          }
#pragma unroll
          for (int q = 0; q < 4; ++q) {
            int slot = ((((jj + 1) << 2) + l4) << 6) + (q << 4) + l15;
            bn[q] = *(const bf16x8*)&Bs[slot << 3];
          }
        }
#pragma unroll
        for (int s = 0; s < 2; ++s)
#pragma unroll
          for (int q = 0; q < 4; ++q)
            acc[s][q] = __builtin_amdgcn_mfma_f32_16x16x32_bf16(a[s], b[q], acc[s][q], 0, 0, 0);
#pragma unroll
        for (int s = 0; s < 2; ++s) a[s] = an[s];
#pragma unroll
        for (int q = 0; q < 4; ++q) b[q] = bn[q];
      }
      __builtin_amdgcn_s_setprio(0);
    }
  }
#pragma unroll
  for (int s = 0; s < 2; ++s)
#pragma unroll
    for (int q = 0; q < 4; ++q) {
      int nr = n0 + wv * 32 + s * 16 + (l4 << 2);
      int p = q * 16 + l15;
#pragma unroll
      for (int i = 0; i < 4; ++i)
        atomicAdd(&out[(size_t)(nr + i) * MPTS + p], acc[s][q][i]);
    }
}

extern "C" void kernel_launch(void* const* d_in, const int* in_sizes, int n_in,
                              void* d_out, int out_size, void* d_ws, size_t ws_size,
                              hipStream_t stream) {
  const float* u    = (const float*)d_in[0];  // [64,64]
  const float* w0   = (const float*)d_in[1];  // [33,128,64]
  const float* b0   = (const float*)d_in[2];  // [33,128,1]
  const float* w    = (const float*)d_in[3];  // [2,33,128,128]
  const float* bias = (const float*)d_in[4];  // [2,33,128,1]
  const float* wf   = (const float*)d_in[5];  // [2048,33,128]
  const float* bfin = (const float*)d_in[6];  // [2048,33,1]
  const float* xi   = (const float*)d_in[7];  // [2048,2080]
  float* out = (float*)d_out;                 // [2048,64]
  char* ws = (char*)d_ws;
  unsigned short* xiT  = (unsigned short*)(ws);             // 8,519,680 B
  unsigned short* Gt2  = (unsigned short*)(ws + 8519680);   // 8,650,752 B
  unsigned short* u1bf = (unsigned short*)(ws + 17170432);  // 540,672 B

  hipFuncSetAttribute(reinterpret_cast<const void*>(&k_prep),
                      hipFuncAttributeMaxDynamicSharedMemorySize, 53760);
  hipFuncSetAttribute(reinterpret_cast<const void*>(&k_conv),
                      hipFuncAttributeMaxDynamicSharedMemorySize, 77824);

  k_prep<<<2113, 256, 53760, stream>>>(xi, xiT, u, w0, b0, w, bias, u1bf, out);
  k_final<<<33 * 32, 256, 0, stream>>>(wf, bfin, u1bf, Gt2);
  k_conv<<<512, 256, 77824, stream>>>(xiT, Gt2, out);
}

// Round 8
// 146.280 us; speedup vs baseline: 1.2532x; 1.0609x over previous
//
#include <hip/hip_runtime.h>

#define WIN 33
#define WIDTH 128
#define MPTS 64
#define NN 2048
#define MM 2048
#define DD 64
#define NQ 2080   // N + 2L

typedef __bf16 bf16x8 __attribute__((ext_vector_type(8)));
typedef float f32x4 __attribute__((ext_vector_type(4)));

__device__ __forceinline__ unsigned short f2bf(float x) {
  union { float f; unsigned int u; } v; v.f = x;
  unsigned int r = v.u + 0x7FFFu + ((v.u >> 16) & 1u);  // RNE
  return (unsigned short)(r >> 16);
}
__device__ __forceinline__ float sigf(float x) { return 1.0f / (1.0f + __expf(-x)); }

// async global->LDS, 16B per lane, fire-and-forget (drained by vmcnt at barrier)
__device__ __forceinline__ void gll16(const unsigned short* g, unsigned short* l) {
  __builtin_amdgcn_global_load_lds(
      (const __attribute__((address_space(1))) unsigned int*)g,
      (__attribute__((address_space(3))) unsigned int*)l, 16, 0, 0);
}

// ------------- fused prep: MLP (bid<33) + transpose (bid>=33) + out-zero ---
// R8: MLP branch restructured as a T14 async pipeline. R7 counters showed
// k_prep = 53us with occupancy 4.9% / VALU 2.3% / HBM 5%: the 33 MLP blocks
// run a serial chain of 5 weight-staging rounds, each with fully-exposed
// load latency (1 wave/SIMD, no TLP). Now each stage's 8 global_load_dwordx4
// are issued to REGISTERS one phase early (during the previous compute), and
// only the convert+ds_write sits between barriers. Same math/tiles/barriers.
__global__ __launch_bounds__(256) void k_prep(const float* __restrict__ xi,
                                              unsigned short* __restrict__ xiT,
                                              const float* __restrict__ u,
                                              const float* __restrict__ w0,
                                              const float* __restrict__ b0,
                                              const float* __restrict__ w,
                                              const float* __restrict__ bias,
                                              unsigned short* __restrict__ u1bf,
                                              float* __restrict__ out) {
  extern __shared__ char smem[];
  int bid = blockIdx.x;
  int tid = threadIdx.x;

  if (bid < 33) {
    // ---------------- MLP branch ----------------
    constexpr int WS = 72;
    constexpr int AS = 136;
    float* biass = (float*)smem;                              // 512 B
    unsigned short* ws   = (unsigned short*)(smem + 512);     // 18,432 B
    unsigned short* actA = (unsigned short*)(smem + 18944);   // 17,408 B
    unsigned short* actB = (unsigned short*)(smem + 36352);   // 17,408 B
    int j = bid;
    int wv = tid >> 6, lane = tid & 63, l15 = lane & 15, l4 = lane >> 4;

    float4 wreg[8];

    auto wload = [&](const float* src) {   // issue 8 float4 loads to regs
#pragma unroll
      for (int r = 0; r < 8; ++r) {
        int c = tid + (r << 8);
        wreg[r] = *(const float4*)&src[(size_t)(c >> 4) * 128 + ((c & 15) << 2)];
      }
    };
    auto wstore = [&]() {                  // convert + LDS write (fast)
#pragma unroll
      for (int r = 0; r < 8; ++r) {
        int c = tid + (r << 8);
        float4 v = wreg[r];
        ushort4 h; h.x = f2bf(v.x); h.y = f2bf(v.y); h.z = f2bf(v.z); h.w = f2bf(v.w);
        *(ushort4*)&ws[(c >> 4) * WS + ((c & 15) << 2)] = h;
      }
    };
    auto mma_half = [&](const unsigned short* bsrc, int hofs, f32x4 (&acc)[2][4]) {
#pragma unroll
      for (int t = 0; t < 2; ++t) {
        int col = (t << 5) + (l4 << 3);
        bf16x8 a[2], b[4];
#pragma unroll
        for (int s = 0; s < 2; ++s)
          a[s] = *(const bf16x8*)&ws[(wv * 32 + s * 16 + l15) * WS + col];
#pragma unroll
        for (int q = 0; q < 4; ++q)
          b[q] = *(const bf16x8*)&bsrc[(q * 16 + l15) * AS + hofs + col];
#pragma unroll
        for (int s = 0; s < 2; ++s)
#pragma unroll
          for (int q = 0; q < 4; ++q)
            acc[s][q] = __builtin_amdgcn_mfma_f32_16x16x32_bf16(a[s], b[q], acc[s][q], 0, 0, 0);
      }
    };
    auto sigstore = [&](f32x4 (&acc)[2][4], unsigned short* dst) {
#pragma unroll
      for (int s = 0; s < 2; ++s)
#pragma unroll
        for (int q = 0; q < 4; ++q) {
          int p = q * 16 + l15;
#pragma unroll
          for (int r = 0; r < 4; ++r) {
            int k = wv * 32 + s * 16 + (l4 << 2) + r;
            dst[p * AS + k] = f2bf(sigf(acc[s][q][r] + biass[k]));
          }
        }
    };

    const float* wb0 = w + ((size_t)0 * WIN + j) * 16384;
    const float* wb1 = w + ((size_t)1 * WIN + j) * 16384;

    // P0: issue u + w0 loads, convert+store, bias0
    {
      float4 ureg[4];
#pragma unroll
      for (int r = 0; r < 4; ++r) {
        int c = tid + (r << 8);
        ureg[r] = *(const float4*)&u[(size_t)(c >> 4) * DD + ((c & 15) << 2)];
      }
#pragma unroll
      for (int r = 0; r < 8; ++r) {
        int c = tid + (r << 8);
        wreg[r] = *(const float4*)&w0[((size_t)j * 128 + (c >> 4)) * DD + ((c & 15) << 2)];
      }
      if (tid < 128) biass[tid] = b0[j * 128 + tid];
#pragma unroll
      for (int r = 0; r < 4; ++r) {
        int c = tid + (r << 8);
        float4 v = ureg[r];
        ushort4 h; h.x = f2bf(v.x); h.y = f2bf(v.y); h.z = f2bf(v.z); h.w = f2bf(v.w);
        *(ushort4*)&actA[(c >> 4) * AS + ((c & 15) << 2)] = h;
      }
#pragma unroll
      for (int r = 0; r < 8; ++r) {
        int c = tid + (r << 8);
        float4 v = wreg[r];
        ushort4 h; h.x = f2bf(v.x); h.y = f2bf(v.y); h.z = f2bf(v.z); h.w = f2bf(v.w);
        *(ushort4*)&ws[(c >> 4) * WS + ((c & 15) << 2)] = h;
      }
    }
    __syncthreads();

    // P1: issue W(L1h0); compute L0 (K=64); sigmoid -> actB
    f32x4 acc0[2][4] = {};
    wload(wb0 + 0);
    mma_half(actA, 0, acc0);
    sigstore(acc0, actB);
    __syncthreads();
    // P2: store W(L1h0); bias[0]
    wstore();
    if (tid < 128) biass[tid] = bias[(size_t)j * 128 + tid];
    __syncthreads();
    // P3: issue W(L1h1); compute L1 h0
    f32x4 acc1[2][4] = {};
    wload(wb0 + 64);
    mma_half(actB, 0, acc1);
    __syncthreads();
    // P4: store W(L1h1)
    wstore();
    __syncthreads();
    // P5: issue W(L2h0); compute L1 h1; sigmoid -> actA
    wload(wb1 + 0);
    mma_half(actB, 64, acc1);
    sigstore(acc1, actA);
    __syncthreads();
    // P6: store W(L2h0); bias[1]
    wstore();
    if (tid < 128) biass[tid] = bias[(size_t)(WIN + j) * 128 + tid];
    __syncthreads();
    // P7: issue W(L2h1); compute L2 h0
    f32x4 acc2[2][4] = {};
    wload(wb1 + 64);
    mma_half(actA, 0, acc2);
    __syncthreads();
    // P8: store W(L2h1)
    wstore();
    __syncthreads();
    // P9: compute L2 h1; sigmoid -> actB
    mma_half(actA, 64, acc2);
    sigstore(acc2, actB);
    __syncthreads();
    // P10: write u1bf
#pragma unroll
    for (int c = tid; c < 1024; c += 256) {
      int p = c >> 4, k8 = (c & 15) << 3;
      uint4 v = *(const uint4*)&actB[p * AS + k8];
      *(uint4*)&u1bf[((size_t)j * MPTS + p) * WIDTH + k8] = v;
    }
  } else {
    // ---------------- transpose branch ----------------
    float* ts = (float*)smem;                // 64*37*4 = 9,472 B
    int t = bid - 33;                        // [0, 2080)
    if (t < 512 && tid < 64) {               // zero out (512 x 1KB = 512KB)
      float4 z = {0.f, 0.f, 0.f, 0.f};
      *(float4*)&out[((size_t)t << 8) + (tid << 2)] = z;
    }
    int qt = t % 65, mt = t / 65;
    int qb = qt * 32;                        // 65 tiles over NQ=2080
    int mb = mt * 64;                        // 32 tiles over M=2048
#pragma unroll
    for (int c = tid; c < 512; c += 256) {   // 64 rows x 8 float4
      int row = c >> 3, c8 = c & 7;
      float4 v = *(const float4*)&xi[(size_t)(mb + row) * NQ + qb + (c8 << 2)];
      ts[row * 37 + (c8 << 2) + 0] = v.x;
      ts[row * 37 + (c8 << 2) + 1] = v.y;
      ts[row * 37 + (c8 << 2) + 2] = v.z;
      ts[row * 37 + (c8 << 2) + 3] = v.w;
    }
    __syncthreads();
#pragma unroll
    for (int c = tid; c < 512; c += 256) {   // 32 q-rows x 16 m-quads
      int r = c >> 4, mq = c & 15;
      ushort4 h;
      h.x = f2bf(ts[(mq * 4 + 0) * 37 + r]);
      h.y = f2bf(ts[(mq * 4 + 1) * 37 + r]);
      h.z = f2bf(ts[(mq * 4 + 2) * 37 + r]);
      h.w = f2bf(ts[(mq * 4 + 3) * 37 + r]);
      *(ushort4*)&xiT[((size_t)mt * NQ + (qb + r)) * 64 + (mq << 2)] = h;
    }
  }
}

// ------------- phase B: Gt2 in k_conv staging order -----------------------
// Gt2[region = mp*2+half][j=33][g=4][p=64][8m], region = 67,584 shorts.
__global__ __launch_bounds__(256) void k_final(const float* __restrict__ wf,
                                               const float* __restrict__ bfin,
                                               const unsigned short* __restrict__ u1bf,
                                               unsigned short* __restrict__ Gt2) {
  constexpr int KP = 136;
  __shared__ unsigned short As[64 * KP];
  __shared__ unsigned short Bs[64 * KP];
  __shared__ float bfs[64];
  int bid = blockIdx.x;                    // 33*32
  int j = bid >> 5;
  int m0 = (bid & 31) << 6;
#pragma unroll
  for (int c = threadIdx.x; c < 64 * 32; c += 256) {
    int row = c >> 5, f4 = c & 31;
    float4 v = *(const float4*)(wf + ((size_t)(m0 + row) * WIN + j) * WIDTH + (f4 << 2));
    ushort4 h;
    h.x = f2bf(v.x); h.y = f2bf(v.y); h.z = f2bf(v.z); h.w = f2bf(v.w);
    *(ushort4*)(&As[row * KP + (f4 << 2)]) = h;
  }
#pragma unroll
  for (int c = threadIdx.x; c < 64 * 16; c += 256) {
    int p = c >> 4, ch = c & 15;
    uint4 v = *(const uint4*)(u1bf + (size_t)(j * MPTS + p) * WIDTH + (ch << 3));
    *(uint4*)(&Bs[p * KP + (ch << 3)]) = v;
  }
  if (threadIdx.x < 64) bfs[threadIdx.x] = bfin[(size_t)(m0 + threadIdx.x) * WIN + j];
  __syncthreads();
  int wv = threadIdx.x >> 6, lane = threadIdx.x & 63;
  int l15 = lane & 15, l4 = lane >> 4;
  f32x4 acc[4] = {};
#pragma unroll
  for (int t = 0; t < 4; ++t) {
    int col = (t << 5) + (l4 << 3);
    bf16x8 a = *(const bf16x8*)(&As[(wv * 16 + l15) * KP + col]);
#pragma unroll
    for (int q = 0; q < 4; ++q) {
      bf16x8 bb = *(const bf16x8*)(&Bs[(q * 16 + l15) * KP + col]);
      acc[q] = __builtin_amdgcn_mfma_f32_16x16x32_bf16(a, bb, acc[q], 0, 0, 0);
    }
  }
  // m_local = wv*16 + l4*4 + i  ->  half = wv>>1, g = (wv&1)*2 + (l4>>1),
  // m8 = (l4&1)*4. Stores hit 2x256B contiguous runs per wave instruction.
  size_t region = (size_t)((bid & 31) << 1) + (wv >> 1);
  int g = ((wv & 1) << 1) + (l4 >> 1);
  int m8 = (l4 & 1) << 2;
  int mb = wv * 16 + (l4 << 2);
#pragma unroll
  for (int q = 0; q < 4; ++q) {
    int p = q * 16 + l15;
    float z0 = acc[q][0] + bfs[mb + 0];
    float z1 = acc[q][1] + bfs[mb + 1];
    float z2 = acc[q][2] + bfs[mb + 2];
    float z3 = acc[q][3] + bfs[mb + 3];
    ushort4 st;
    st.x = f2bf(sigf(z0)); st.y = f2bf(sigf(z1));
    st.z = f2bf(sigf(z2)); st.w = f2bf(sigf(z3));
    *(ushort4*)(&Gt2[region * 67584 + ((size_t)(j * 4 + g) * 64 + p) * 8 + m8]) = st;
  }
}

// ------------- phase C: out[n,p] += sum_{j,m} xiT[n+j,m] * Gt2[j,p,m] ------
// Exact R5 structure (best measured: inside 153.3us total). Rotated 2-phase
// pipeline, Bs double-buffered, next phase's global_load_lds issued right
// after the barrier, before compute. No setprio (R7: neutral/-2us).
__global__ __launch_bounds__(256) void k_conv(const unsigned short* __restrict__ xiT,
                                              const unsigned short* __restrict__ Gt2,
                                              float* __restrict__ out) {
  extern __shared__ unsigned short lds[];
  unsigned short* As = lds;                // [160][64] swizzled = 20,480 B
  int bid = blockIdx.x;
  int mp = bid & 31;                       // bid%8 == mp%8 -> same-B blocks share an XCD
  int n0 = (bid >> 5) << 7;                // 16 n-tiles of 128
  int tid = threadIdx.x;
  int wv = tid >> 6, lane = tid & 63, l15 = lane & 15, l4 = lane >> 4;

  // ---- stage A once: contiguous 1KB per instr; XOR permute (c ^= row&7)
  const unsigned short* Abase = xiT + (size_t)mp * (NQ * 64) + (size_t)n0 * 64;
#pragma unroll
  for (int k = 0; k < 5; ++k) {
    int instr = wv * 5 + k;                // 20 wave-instructions
    int s = (instr << 6) + lane;
    int row = s >> 3;
    int c = (s & 7) ^ (row & 7);
    gll16(Abase + (size_t)row * 64 + (c << 3), As + (instr << 9));
  }

  // phase tables: t = half*5 + p
  constexpr int JBT[10]  = {0, 7, 14, 21, 28, 0, 7, 14, 21, 28};
  constexpr int CNTT[10] = {7, 7, 7, 7, 5, 7, 7, 7, 7, 5};
  constexpr int HFT[10]  = {0, 0, 0, 0, 0, 1, 1, 1, 1, 1};

  const unsigned short* Rb0 = Gt2 + (size_t)(mp << 1) * 67584;        // half 0
  const unsigned short* Rb1 = Gt2 + (size_t)((mp << 1) + 1) * 67584;  // half 1

  // ---- prologue: issue B(phase 0) into buf0
  {
    const unsigned short* Bb = Rb0;        // jb=0
#pragma unroll
    for (int k = 0; k < 7; ++k) {
      int instr = wv * 7 + k;
      gll16(Bb + (((instr << 6) + lane) << 3), lds + 10240 + (instr << 9));
    }
  }

  f32x4 acc[2][4] = {};
#pragma unroll
  for (int t = 0; t < 10; ++t) {
    __syncthreads();   // drains own vmcnt(0): A + B(t) ready; all waves done
                       // reading the buffer about to be overwritten.
    if (t < 9) {       // issue B(t+1) into buf[(t+1)&1]; lands during compute(t)
      const int jbn = JBT[t + 1], cntn = CNTT[t + 1];
      const unsigned short* Bb =
          (HFT[t + 1] ? Rb1 : Rb0) + ((size_t)jbn << 11);
      unsigned short* Bst = lds + 10240 + ((t + 1) & 1) * 14336;
#pragma unroll
      for (int k = 0; k < cntn; ++k) {
        int instr = wv * cntn + k;
        gll16(Bb + (((instr << 6) + lane) << 3), Bst + (instr << 9));
      }
    }
    // ---- compute phase t from buf[t&1]
    {
      const int jb = JBT[t], cnt = CNTT[t], h4 = HFT[t] << 2;
      const unsigned short* Bs = lds + 10240 + (t & 1) * 14336;
      bf16x8 a[2], b[4];
#pragma unroll
      for (int s = 0; s < 2; ++s) {
        int row = wv * 32 + s * 16 + l15 + jb;
        a[s] = *(const bf16x8*)&As[row * 64 + (((h4 | l4) ^ (row & 7)) << 3)];
      }
#pragma unroll
      for (int q = 0; q < 4; ++q) {
        int slot = (l4 << 6) + (q << 4) + l15;
        b[q] = *(const bf16x8*)&Bs[slot << 3];
      }
#pragma unroll
      for (int jj = 0; jj < cnt; ++jj) {
        bf16x8 an[2], bn[4];
        if (jj < cnt - 1) {                // prefetch j+1 while computing j
#pragma unroll
          for (int s = 0; s < 2; ++s) {
            int row = wv * 32 + s * 16 + l15 + jb + jj + 1;
            an[s] = *(const bf16x8*)&As[row * 64 + (((h4 | l4) ^ (row & 7)) << 3)];
          }
#pragma unroll
          for (int q = 0; q < 4; ++q) {
            int slot = ((((jj + 1) << 2) + l4) << 6) + (q << 4) + l15;
            bn[q] = *(const bf16x8*)&Bs[slot << 3];
          }
        }
#pragma unroll
        for (int s = 0; s < 2; ++s)
#pragma unroll
          for (int q = 0; q < 4; ++q)
            acc[s][q] = __builtin_amdgcn_mfma_f32_16x16x32_bf16(a[s], b[q], acc[s][q], 0, 0, 0);
#pragma unroll
        for (int s = 0; s < 2; ++s) a[s] = an[s];
#pragma unroll
        for (int q = 0; q < 4; ++q) b[q] = bn[q];
      }
    }
  }
#pragma unroll
  for (int s = 0; s < 2; ++s)
#pragma unroll
    for (int q = 0; q < 4; ++q) {
      int nr = n0 + wv * 32 + s * 16 + (l4 << 2);
      int p = q * 16 + l15;
#pragma unroll
      for (int i = 0; i < 4; ++i)
        atomicAdd(&out[(size_t)(nr + i) * MPTS + p], acc[s][q][i]);
    }
}

extern "C" void kernel_launch(void* const* d_in, const int* in_sizes, int n_in,
                              void* d_out, int out_size, void* d_ws, size_t ws_size,
                              hipStream_t stream) {
  const float* u    = (const float*)d_in[0];  // [64,64]
  const float* w0   = (const float*)d_in[1];  // [33,128,64]
  const float* b0   = (const float*)d_in[2];  // [33,128,1]
  const float* w    = (const float*)d_in[3];  // [2,33,128,128]
  const float* bias = (const float*)d_in[4];  // [2,33,128,1]
  const float* wf   = (const float*)d_in[5];  // [2048,33,128]
  const float* bfin = (const float*)d_in[6];  // [2048,33,1]
  const float* xi   = (const float*)d_in[7];  // [2048,2080]
  float* out = (float*)d_out;                 // [2048,64]
  char* ws = (char*)d_ws;
  unsigned short* xiT  = (unsigned short*)(ws);             // 8,519,680 B
  unsigned short* Gt2  = (unsigned short*)(ws + 8519680);   // 8,650,752 B
  unsigned short* u1bf = (unsigned short*)(ws + 17170432);  // 540,672 B

  hipFuncSetAttribute(reinterpret_cast<const void*>(&k_prep),
                      hipFuncAttributeMaxDynamicSharedMemorySize, 53760);
  hipFuncSetAttribute(reinterpret_cast<const void*>(&k_conv),
                      hipFuncAttributeMaxDynamicSharedMemorySize, 77824);

  k_prep<<<2113, 256, 53760, stream>>>(xi, xiT, u, w0, b0, w, bias, u1bf, out);
  k_final<<<33 * 32, 256, 0, stream>>>(wf, bfin, u1bf, Gt2);
  k_conv<<<512, 256, 77824, stream>>>(xiT, Gt2, out);
}